// Round 2
// baseline (273.822 us; speedup 1.0000x reference)
//
#include <hip/hip_runtime.h>
#include <math.h>

#define N_NODES 10000
#define N_EDGES 160000
#define N_FEAT  512
#define HEADS   8
#define HID     128

typedef __attribute__((ext_vector_type(8))) short bf16x8;
typedef __attribute__((ext_vector_type(4))) float f32x4;
typedef __attribute__((ext_vector_type(2))) float v2f;
typedef __attribute__((ext_vector_type(4))) int i32x4;

// ---------------------------------------------------------------------------
// fp32 <-> bf16 helpers
// ---------------------------------------------------------------------------
__device__ inline unsigned short f2bf_rne(float f) {
  unsigned int u = __float_as_uint(f);
  unsigned int r = u + 0x7fffu + ((u >> 16) & 1u);
  return (unsigned short)(r >> 16);
}
__device__ inline float bf2f(unsigned int b) {
  return __uint_as_float(b << 16);
}

// ---------------------------------------------------------------------------
// split body: fp32 [R][K] -> hi/lo bf16 in MFMA-fragment-major layout.
// lo == nullptr skips the lo plane (A operand is consumed at bf16 only).
// ---------------------------------------------------------------------------
__device__ inline void split_body(const float* __restrict__ in,
                                  unsigned short* __restrict__ hi,
                                  unsigned short* __restrict__ lo,
                                  int R, int K8, int idx) {
  int r = idx & 15;
  int t = idx >> 4;
  int kq = t % K8;
  int rb = t / K8;
  int row = rb * 16 + r;
  float v[8] = {0.f, 0.f, 0.f, 0.f, 0.f, 0.f, 0.f, 0.f};
  if (row < R) {
    const float* p = in + (size_t)row * (K8 * 8) + kq * 8;
    float4 a = *(const float4*)p;
    float4 b = *(const float4*)(p + 4);
    v[0] = a.x; v[1] = a.y; v[2] = a.z; v[3] = a.w;
    v[4] = b.x; v[5] = b.y; v[6] = b.z; v[7] = b.w;
  }
  union { unsigned short u[8]; int4 v4; } H, L;
  #pragma unroll
  for (int e = 0; e < 8; ++e) {
    unsigned short hb_ = f2bf_rne(v[e]);
    H.u[e] = hb_;
    L.u[e] = f2bf_rne(v[e] - bf2f(hb_));
  }
  *(int4*)&hi[(size_t)idx * 8] = H.v4;
  if (lo) *(int4*)&lo[(size_t)idx * 8] = L.v4;
}

// Combined A split + W split + CSR degree count in ONE dispatch.
__global__ __launch_bounds__(256)
void split_frag2(const float* __restrict__ in1, unsigned short* __restrict__ hi1,
                 unsigned short* __restrict__ lo1, int R1, int K81, int total1,
                 int nb1,
                 const float* __restrict__ in2, unsigned short* __restrict__ hi2,
                 unsigned short* __restrict__ lo2, int R2, int K82, int total2,
                 int nb2,
                 const int* __restrict__ edst, int* __restrict__ deg, int E) {
  if ((int)blockIdx.x < nb1) {
    int idx = blockIdx.x * 256 + threadIdx.x;
    if (idx < total1) split_body(in1, hi1, lo1, R1, K81, idx);
  } else if ((int)blockIdx.x < nb1 + nb2) {
    int idx = (blockIdx.x - nb1) * 256 + threadIdx.x;
    if (idx < total2) split_body(in2, hi2, lo2, R2, K82, idx);
  } else {
    int e = (blockIdx.x - nb1 - nb2) * 256 + threadIdx.x;
    if (e < E) atomicAdd(&deg[edst[e]], 1);
  }
}

// ---------------------------------------------------------------------------
// LDS-free split-bf16 MFMA GEMM.  R1 change: A consumed at bf16 only
// (dropped al*bh term: |error| ~2^-9 relative, below the bf16 rounding the
// hb store applies anyway), B stays hi+lo split (scores si/sj keep ~fp32 B).
// 2 MFMAs + 12 loads per (i,j)-step instead of 3 + 16.  Stores are
// NONTEMPORAL so the 20.5MB hb write stream stops evicting the A/B operand
// tiles from per-XCD L2 (A-hi 1.3MB + B 2MB now fit the 4MB L2).
// ---------------------------------------------------------------------------
__global__ __launch_bounds__(128, 3)
void gemm_frag(const unsigned short* __restrict__ Afh,
               const unsigned short* __restrict__ Afl,
               const unsigned short* __restrict__ Bfh,
               const unsigned short* __restrict__ Bfl,
               const float* __restrict__ avec,
               unsigned short* __restrict__ hb,
               float* __restrict__ si, float* __restrict__ sj,
               int M, int K) {
  __shared__ float rsi[64][2];
  __shared__ float rsj[64][2];
  int tid = threadIdx.x;
  int wave = tid >> 6, lane = tid & 63;
  int r = lane & 15, q = lane >> 4;

  int blk = blockIdx.x;
  int rr = blk & 7, gg = blk >> 3;
  int head = gg & 7;
  int mtile = (gg >> 3) * 8 + rr;     // blk%8 == mtile%8 -> XCD affinity
  int m0 = mtile * 64;
  int wn = wave * 64;
  int K8 = K >> 3;

  const bf16x8* pAh = (const bf16x8*)Afh;
  const bf16x8* pBh = (const bf16x8*)Bfh;
  const bf16x8* pBl = (const bf16x8*)Bfl;
  size_t rstep = (size_t)K8 * 16;
  size_t aidx = (size_t)(m0 >> 4) * rstep + (size_t)q * 16 + r;
  size_t bidx = (size_t)(head * 8 + (wn >> 4)) * rstep + (size_t)q * 16 + r;

  f32x4 acc[4][4] = {};

  for (int k0 = 0; k0 < K; k0 += 32, aidx += 64, bidx += 64) {
    bf16x8 ah[4], bh[4], bl[4];
    #pragma unroll
    for (int i = 0; i < 4; ++i) {
      ah[i] = pAh[aidx + i * rstep];
      bh[i] = pBh[bidx + i * rstep];
      bl[i] = pBl[bidx + i * rstep];
    }
    #pragma unroll
    for (int i = 0; i < 4; ++i)
      #pragma unroll
      for (int j = 0; j < 4; ++j) {
        acc[i][j] = __builtin_amdgcn_mfma_f32_16x16x32_bf16(ah[i], bh[j], acc[i][j], 0, 0, 0);
        acc[i][j] = __builtin_amdgcn_mfma_f32_16x16x32_bf16(ah[i], bl[j], acc[i][j], 0, 0, 0);
      }
  }

  // --- epilogue: C/D layout col = r, row = q*4 + reg (per 16x16 frag) ---
  const float* av = avec + (size_t)head * (2 * HID);
  float aiv[4], ajv[4];
  #pragma unroll
  for (int j = 0; j < 4; ++j) {
    int c = wn + j * 16 + r;
    aiv[j] = av[c];
    ajv[j] = av[HID + c];
  }
  #pragma unroll
  for (int i = 0; i < 4; ++i) {
    #pragma unroll
    for (int reg = 0; reg < 4; ++reg) {
      int lrow = i * 16 + q * 4 + reg;
      int row = m0 + lrow;
      float vsi = 0.f, vsj = 0.f;
      #pragma unroll
      for (int j = 0; j < 4; ++j) {
        float v = acc[i][j][reg];
        vsi = fmaf(v, aiv[j], vsi);
        vsj = fmaf(v, ajv[j], vsj);
        if (row < M)
          __builtin_nontemporal_store(
              f2bf_rne(v), &hb[((size_t)head * M + row) * HID + wn + j * 16 + r]);
      }
      #pragma unroll
      for (int o = 8; o >= 1; o >>= 1) {
        vsi += __shfl_xor(vsi, o);
        vsj += __shfl_xor(vsj, o);
      }
      if (r == 0) {
        rsi[lrow][wave] = vsi;
        rsj[lrow][wave] = vsj;
      }
    }
  }
  __syncthreads();
  if (tid < 64) {
    int row = m0 + tid;
    if (row < M) {
      __builtin_nontemporal_store(rsi[tid][0] + rsi[tid][1], &si[(size_t)head * M + row]);
      __builtin_nontemporal_store(rsj[tid][0] + rsj[tid][1], &sj[(size_t)head * M + row]);
    }
  }
}

// ---------------------------------------------------------------------------
// CSR build (count fused into split_frag2)
// ---------------------------------------------------------------------------
__global__ __launch_bounds__(1024)
void scan_kernel(const int* __restrict__ deg, int* __restrict__ off, int N) {
  __shared__ int sums[1024];
  const int PER = 10;
  int tid = threadIdx.x;
  int base = tid * PER;
  int loc[PER];
  int run = 0;
  #pragma unroll
  for (int j = 0; j < PER; ++j) {
    int v = (base + j < N) ? deg[base + j] : 0;
    run += v;
    loc[j] = run;
  }
  sums[tid] = run;
  __syncthreads();
  for (int o = 1; o < 1024; o <<= 1) {
    int v = (tid >= o) ? sums[tid - o] : 0;
    __syncthreads();
    sums[tid] += v;
    __syncthreads();
  }
  int ex = sums[tid] - run;
  if (tid == 0) off[0] = 0;
  #pragma unroll
  for (int j = 0; j < PER; ++j)
    if (base + j < N) off[base + j + 1] = ex + loc[j];
}

__global__ void fill_kernel(const int* __restrict__ src, const int* __restrict__ dst,
                            const int* __restrict__ off, int* __restrict__ cursor,
                            int* __restrict__ ssrc, int E) {
  int e = blockIdx.x * blockDim.x + threadIdx.x;
  if (e < E) {
    int d = dst[e];
    int p = atomicAdd(&cursor[d], 1);
    ssrc[off[d] + p] = src[e];
  }
}

// ---------------------------------------------------------------------------
// FUSED softmax + aggregation: one wave = FOUR dst nodes (16 lanes per dst)
// of one head.  aggb store is NONTEMPORAL: single-consumer stream, keeps the
// hb gather working set resident in this XCD's L2.
// ---------------------------------------------------------------------------
__global__ __launch_bounds__(512)
void gat_aggregate8(const unsigned short* __restrict__ hb,
                    const float* __restrict__ si, const float* __restrict__ sj,
                    const int* __restrict__ off, const int* __restrict__ ssrc,
                    unsigned short* __restrict__ aggb, int N) {
  __shared__ int2 prs[8][4][32];   // [wave][group][edge-slot] (src, w)
  int head = blockIdx.x & 7;
  int wv = threadIdx.x >> 6;
  int lane = threadIdx.x & 63;
  int grp = lane >> 4;
  int sl = lane & 15;
  int n = (blockIdx.x >> 3) * 32 + wv * 4 + grp;
  const unsigned short* hbase = hb + (size_t)head * N * HID;
  const float* sjh = sj + (size_t)head * N;
  bool nv = n < N;
  int begin = 0, deg = 0;
  float s_i = 0.f;
  if (nv) {
    begin = off[n];
    deg = off[n + 1] - begin;
    s_i = si[(size_t)head * N + n];
  }

  // --- phase 1: per-lane edge scores, 2 slots (covers deg <= 32) ---
  int src0 = 0, src1 = 0;
  float sc0 = -INFINITY, sc1 = -INFINITY;
  if (sl < deg) {
    src0 = ssrc[begin + sl];
    float t = s_i + sjh[src0];
    sc0 = t > 0.f ? t : 0.01f * t;
  }
  if (16 + sl < deg) {
    src1 = ssrc[begin + 16 + sl];
    float t = s_i + sjh[src1];
    sc1 = t > 0.f ? t : 0.01f * t;
  }
  float m = fmaxf(sc0, sc1);
  for (int e2 = 32 + sl; e2 < deg; e2 += 16) {      // rare tail max
    int s = ssrc[begin + e2];
    float t = s_i + sjh[s];
    t = t > 0.f ? t : 0.01f * t;
    m = fmaxf(m, t);
  }
  #pragma unroll
  for (int o = 1; o <= 8; o <<= 1) m = fmaxf(m, __shfl_xor(m, o));

  float w0 = (sl < deg) ? __expf(sc0 - m) : 0.f;
  float w1 = (16 + sl < deg) ? __expf(sc1 - m) : 0.f;
  float den = w0 + w1;
  for (int e2 = 32 + sl; e2 < deg; e2 += 16) {      // rare tail denom
    int s = ssrc[begin + e2];
    float t = s_i + sjh[s];
    t = t > 0.f ? t : 0.01f * t;
    den += __expf(t - m);
  }
  #pragma unroll
  for (int o = 1; o <= 8; o <<= 1) den += __shfl_xor(den, o);

  // stage pairs (w=0 beyond deg; src=0 -> safe dummy gather)
  prs[wv][grp][sl] = make_int2(src0, __float_as_int(w0));
  prs[wv][grp][16 + sl] = make_int2(src1, __float_as_int(w1));
  // wave-synchronous LDS: ensure writes land + block compiler reorder.
  __asm__ volatile("s_waitcnt lgkmcnt(0)" ::: "memory");

  // --- gather: 16 lanes cover the 128-dim row, 4 edges in flight ---
  v2f a01 = {0.f, 0.f}, a23 = {0.f, 0.f}, a45 = {0.f, 0.f}, a67 = {0.f, 0.f};
  int dmin = deg < 32 ? deg : 32;
  for (int e0 = 0; e0 < dmin; e0 += 4) {            // slots e0..e0+3 <= 31 always init'd
    int2 p[4];
    #pragma unroll
    for (int u = 0; u < 4; ++u) p[u] = prs[wv][grp][e0 + u];
    int4 pv[4];
    #pragma unroll
    for (int u = 0; u < 4; ++u)
      pv[u] = *(const int4*)&hbase[(size_t)p[u].x * HID + sl * 8];
    #pragma unroll
    for (int u = 0; u < 4; ++u) {
      float w = __int_as_float(p[u].y);
      v2f w2 = {w, w};
      int4 q = pv[u];
      v2f t0 = {bf2f((unsigned)q.x & 0xffffu), __uint_as_float((unsigned)q.x & 0xffff0000u)};
      v2f t1 = {bf2f((unsigned)q.y & 0xffffu), __uint_as_float((unsigned)q.y & 0xffff0000u)};
      v2f t2 = {bf2f((unsigned)q.z & 0xffffu), __uint_as_float((unsigned)q.z & 0xffff0000u)};
      v2f t3 = {bf2f((unsigned)q.w & 0xffffu), __uint_as_float((unsigned)q.w & 0xffff0000u)};
      a01 += w2 * t0;                 // v_pk_fma_f32
      a23 += w2 * t1;
      a45 += w2 * t2;
      a67 += w2 * t3;
    }
  }
  // rare tail: deg > 32, recompute weight (uniform across the 16-lane group)
  for (int e2 = 32; e2 < deg; ++e2) {
    int s = ssrc[begin + e2];
    float t = s_i + sjh[s];
    t = t > 0.f ? t : 0.01f * t;
    float w = __expf(t - m);
    v2f w2 = {w, w};
    int4 q = *(const int4*)&hbase[(size_t)s * HID + sl * 8];
    v2f t0 = {bf2f((unsigned)q.x & 0xffffu), __uint_as_float((unsigned)q.x & 0xffff0000u)};
    v2f t1 = {bf2f((unsigned)q.y & 0xffffu), __uint_as_float((unsigned)q.y & 0xffff0000u)};
    v2f t2 = {bf2f((unsigned)q.z & 0xffffu), __uint_as_float((unsigned)q.z & 0xffff0000u)};
    v2f t3 = {bf2f((unsigned)q.w & 0xffffu), __uint_as_float((unsigned)q.w & 0xffff0000u)};
    a01 += w2 * t0; a23 += w2 * t1; a45 += w2 * t2; a67 += w2 * t3;
  }

  // --- epilogue: each lane owns 8 dims; all 64 lanes store ---
  if (nv) {
    float inv = den > 0.f ? 1.0f / den : 0.f;
    union { unsigned short u[8]; i32x4 v4; } P;
    P.u[0] = f2bf_rne(a01.x * inv); P.u[1] = f2bf_rne(a01.y * inv);
    P.u[2] = f2bf_rne(a23.x * inv); P.u[3] = f2bf_rne(a23.y * inv);
    P.u[4] = f2bf_rne(a45.x * inv); P.u[5] = f2bf_rne(a45.y * inv);
    P.u[6] = f2bf_rne(a67.x * inv); P.u[7] = f2bf_rne(a67.y * inv);
    __builtin_nontemporal_store(
        P.v4, (i32x4*)&aggb[((size_t)head * N + n) * HID + sl * 8]);
  }
}

// ---------------------------------------------------------------------------
// Head mean + ELU (bf16 aggbuf), writing layer-2 A in frag-major split form
// (hi plane only — gemm consumes A at bf16), FUSED with the W2 split.
// ---------------------------------------------------------------------------
__global__ __launch_bounds__(256)
void headmean_frag_w2(const unsigned short* __restrict__ aggb,
                      unsigned short* __restrict__ hiA,
                      int N, int nbHM,
                      const float* __restrict__ W2, unsigned short* __restrict__ hiB,
                      unsigned short* __restrict__ loB, int totalB) {
  if ((int)blockIdx.x >= nbHM) {
    int idx = (blockIdx.x - nbHM) * 256 + threadIdx.x;
    if (idx < totalB) split_body(W2, hiB, loB, HEADS * HID, 16, idx);
    return;
  }
  int idx = blockIdx.x * 256 + threadIdx.x;   // (rb,kq,r), K8=16
  int total = ((N + 15) / 16) * 256;
  if (idx >= total) return;
  int r = idx & 15;
  int kq = (idx >> 4) & 15;
  int rb = idx >> 8;
  int n = rb * 16 + r;
  float s[8] = {0.f, 0.f, 0.f, 0.f, 0.f, 0.f, 0.f, 0.f};
  if (n < N) {
    #pragma unroll
    for (int hh = 0; hh < HEADS; ++hh) {
      int4 pv = *(const int4*)&aggb[((size_t)hh * N + n) * HID + kq * 8];
      s[0] += bf2f((unsigned)pv.x & 0xffffu);
      s[1] += __uint_as_float((unsigned)pv.x & 0xffff0000u);
      s[2] += bf2f((unsigned)pv.y & 0xffffu);
      s[3] += __uint_as_float((unsigned)pv.y & 0xffff0000u);
      s[4] += bf2f((unsigned)pv.z & 0xffffu);
      s[5] += __uint_as_float((unsigned)pv.z & 0xffff0000u);
      s[6] += bf2f((unsigned)pv.w & 0xffffu);
      s[7] += __uint_as_float((unsigned)pv.w & 0xffff0000u);
    }
  }
  union { unsigned short u[8]; int4 v4; } H;
  #pragma unroll
  for (int e = 0; e < 8; ++e) {
    float v = s[e] * (1.0f / HEADS);
    v = v > 0.f ? v : (__expf(v) - 1.0f);   // ELU
    H.u[e] = f2bf_rne(v);
  }
  *(int4*)&hiA[(size_t)idx * 8] = H.v4;
}

// ---------------------------------------------------------------------------
// Layer-2 tail: head mean + ELU + graph pooling fused (no emb2 materialized).
// ---------------------------------------------------------------------------
__global__ __launch_bounds__(256)
void headmean_pool(const unsigned short* __restrict__ aggb, float* __restrict__ g,
                   int N) {
  __shared__ float sm[16][128];
  int t = threadIdx.x;
  int nl = t >> 4, dg = t & 15;
  int n = blockIdx.x * 16 + nl;
  float v[8] = {0.f, 0.f, 0.f, 0.f, 0.f, 0.f, 0.f, 0.f};
  if (n < N) {
    #pragma unroll
    for (int hh = 0; hh < HEADS; ++hh) {
      int4 pv = *(const int4*)&aggb[((size_t)hh * N + n) * HID + dg * 8];
      v[0] += bf2f((unsigned)pv.x & 0xffffu);
      v[1] += __uint_as_float((unsigned)pv.x & 0xffff0000u);
      v[2] += bf2f((unsigned)pv.y & 0xffffu);
      v[3] += __uint_as_float((unsigned)pv.y & 0xffff0000u);
      v[4] += bf2f((unsigned)pv.z & 0xffffu);
      v[5] += __uint_as_float((unsigned)pv.z & 0xffff0000u);
      v[6] += bf2f((unsigned)pv.w & 0xffffu);
      v[7] += __uint_as_float((unsigned)pv.w & 0xffff0000u);
    }
    #pragma unroll
    for (int e = 0; e < 8; ++e) {
      float x = v[e] * (1.0f / HEADS);
      v[e] = x > 0.f ? x : (__expf(x) - 1.0f);   // ELU
    }
  }
  #pragma unroll
  for (int e = 0; e < 8; ++e) sm[nl][dg * 8 + e] = v[e];
  __syncthreads();
  if (t < 128) {
    float s = 0.f;
    #pragma unroll
    for (int nn = 0; nn < 16; ++nn) s += sm[nn][t];
    atomicAdd(&g[t], s);
  }
}

// ---------------------------------------------------------------------------
// LayerNorm + MLP head
// ---------------------------------------------------------------------------
__global__ __launch_bounds__(128)
void mlp_kernel(const float* __restrict__ g, const float* __restrict__ ln_g,
                const float* __restrict__ ln_b, const float* __restrict__ Wl1,
                const float* __restrict__ bl1, const float* __restrict__ Wl2,
                const float* __restrict__ bl2, const float* __restrict__ Wl3,
                const float* __restrict__ bl3, float* __restrict__ out, float invN) {
  __shared__ float red[128];
  __shared__ float gn[128];
  __shared__ float x1[64];
  __shared__ float x2[16];
  int t = threadIdx.x;
  float gg = g[t] * invN;
  red[t] = gg;
  __syncthreads();
  for (int o = 64; o > 0; o >>= 1) {
    if (t < o) red[t] += red[t + o];
    __syncthreads();
  }
  float mu = red[0] * (1.0f / HID);
  __syncthreads();
  float dv = gg - mu;
  red[t] = dv * dv;
  __syncthreads();
  for (int o = 64; o > 0; o >>= 1) {
    if (t < o) red[t] += red[t + o];
    __syncthreads();
  }
  float var = red[0] * (1.0f / HID);
  gn[t] = dv / sqrtf(var + 1e-5f) * ln_g[t] + ln_b[t];
  __syncthreads();
  if (t < 64) {
    float s = bl1[t];
    for (int k = 0; k < 128; ++k) s += Wl1[t * 128 + k] * gn[k];
    x1[t] = s > 0.f ? s : 0.01f * s;
  }
  __syncthreads();
  if (t < 16) {
    float s = bl2[t];
    for (int k = 0; k < 64; ++k) s += Wl2[t * 64 + k] * x1[k];
    x2[t] = s > 0.f ? s : 0.01f * s;
  }
  __syncthreads();
  if (t < 16) {
    float s = bl3[t];
    for (int k = 0; k < 16; ++k) s += Wl3[t * 16 + k] * x2[k];
    out[t] = s > 0.f ? s : 0.f;
  }
}

// ---------------------------------------------------------------------------
extern "C" void kernel_launch(void* const* d_in, const int* in_sizes, int n_in,
                              void* d_out, int out_size, void* d_ws, size_t ws_size,
                              hipStream_t stream) {
  const float* x    = (const float*)d_in[0];
  const int*   esrc = (const int*)d_in[1];
  const int*   edst = (const int*)d_in[2];
  const float* W1   = (const float*)d_in[3];
  const float* a1   = (const float*)d_in[4];
  const float* W2   = (const float*)d_in[5];
  const float* a2   = (const float*)d_in[6];
  const float* ln_g = (const float*)d_in[7];
  const float* ln_b = (const float*)d_in[8];
  const float* Wl1  = (const float*)d_in[9];
  const float* bl1  = (const float*)d_in[10];
  const float* Wl2  = (const float*)d_in[11];
  const float* bl2  = (const float*)d_in[12];
  const float* Wl3  = (const float*)d_in[13];
  const float* bl3  = (const float*)d_in[14];
  float* out = (float*)d_out;

  const int RBPAD = 640;  // row-blocks padded (10240 rows) for in-bounds frags

  // workspace carve-up (g, deg, cur contiguous -> one memset)
  unsigned short* aggb = (unsigned short*)d_ws;                 // 20.5 MB
  float* si   = (float*)(aggb + (size_t)N_NODES * HEADS * HID); // 80,000
  float* sj   = si + N_NODES * HEADS;                           // 80,000
  float* g    = sj + N_NODES * HEADS;                           // 128
  int*   deg  = (int*)(g + 128);                                // 10,000
  int*   cur  = deg + N_NODES;                                  // 10,000
  int*   off  = cur + N_NODES;                                  // 10,001 -> pad 10,004
  int*   ssrc = off + 10004;                                    // 160,000
  unsigned short* Afh = (unsigned short*)(ssrc + N_EDGES);      // 640*64*128 us
  unsigned short* Afl = Afh + (size_t)RBPAD * 64 * 128;         // (unused by gemm now)
  unsigned short* Bfh = Afl + (size_t)RBPAD * 64 * 128;
  unsigned short* Bfl = Bfh + (size_t)64 * 64 * 128;
  unsigned short* hb  = Bfl + (size_t)64 * 64 * 128;            // 20.5 MB

  // zero g + deg + cur in ONE memset (contiguous)
  hipMemsetAsync(g, 0, 128 * sizeof(float) + 2 * N_NODES * sizeof(int), stream);

  int gemmGrid = 160 * HEADS;                     // 1280 blocks of 128 threads
  int aggGrid = ((N_NODES + 31) / 32) * 8;        // 2504 blocks: 32 dst x 1 head each

  // ---- Layer 1: fused A-split + W1-split + CSR count in one dispatch ----
  {
    int totalA = RBPAD * 64 * 16;             // K8=64
    int nbA = (totalA + 255) / 256;           // 2560
    int totalB = 64 * 64 * 16;                // 1024 rows, K8=64
    int nbB = (totalB + 255) / 256;           // 256
    int nbE = (N_EDGES + 255) / 256;          // 625
    split_frag2<<<nbA + nbB + nbE, 256, 0, stream>>>(
        x, Afh, (unsigned short*)nullptr, N_NODES, 64, totalA, nbA,
        W1, Bfh, Bfl, HEADS * HID, 64, totalB, nbB,
        edst, deg, N_EDGES);
  }
  scan_kernel<<<1, 1024, 0, stream>>>(deg, off, N_NODES);
  fill_kernel<<<(N_EDGES + 255) / 256, 256, 0, stream>>>(esrc, edst, off, cur, ssrc, N_EDGES);

  gemm_frag<<<gemmGrid, 128, 0, stream>>>(Afh, Afl, Bfh, Bfl, a1, hb,
                                          si, sj, N_NODES, N_FEAT);
  gat_aggregate8<<<aggGrid, 512, 0, stream>>>(hb, si, sj, off, ssrc, aggb, N_NODES);
  {
    int nbHM = ((N_NODES + 15) / 16 * 256 + 255) / 256;   // 625
    int totalB = 64 * 16 * 16;                            // W2: 1024 rows, K8=16
    int nbB = (totalB + 255) / 256;                       // 64
    headmean_frag_w2<<<nbHM + nbB, 256, 0, stream>>>(aggb, Afh, N_NODES, nbHM,
                                                     W2, Bfh, Bfl, totalB);
  }

  // ---- Layer 2 ----
  gemm_frag<<<gemmGrid, 128, 0, stream>>>(Afh, Afl, Bfh, Bfl, a2, hb,
                                          si, sj, N_NODES, HID);
  gat_aggregate8<<<aggGrid, 512, 0, stream>>>(hb, si, sj, off, ssrc, aggb, N_NODES);

  // ---- fused head-mean + pooling + MLP head ----
  headmean_pool<<<(N_NODES + 15) / 16, 256, 0, stream>>>(aggb, g, N_NODES);
  mlp_kernel<<<1, 128, 0, stream>>>(g, ln_g, ln_b, Wl1, bl1, Wl2, bl2, Wl3, bl3,
                                    out, 1.0f / N_NODES);
}

// Round 3
// 248.006 us; speedup vs baseline: 1.1041x; 1.1041x over previous
//
#include <hip/hip_runtime.h>
#include <math.h>

#define N_NODES 10000
#define N_EDGES 160000
#define N_FEAT  512
#define HEADS   8
#define HID     128

typedef __attribute__((ext_vector_type(8))) short bf16x8;
typedef __attribute__((ext_vector_type(4))) float f32x4;
typedef __attribute__((ext_vector_type(2))) float v2f;

// ---------------------------------------------------------------------------
// fp32 <-> bf16 helpers
// ---------------------------------------------------------------------------
__device__ inline unsigned short f2bf_rne(float f) {
  unsigned int u = __float_as_uint(f);
  unsigned int r = u + 0x7fffu + ((u >> 16) & 1u);
  return (unsigned short)(r >> 16);
}
__device__ inline float bf2f(unsigned int b) {
  return __uint_as_float(b << 16);
}

// ---------------------------------------------------------------------------
// split body: fp32 [R][K] -> hi/lo bf16 in MFMA-fragment-major layout.
// lo == nullptr skips the lo plane (A operand is consumed at bf16 only).
// ---------------------------------------------------------------------------
__device__ inline void split_body(const float* __restrict__ in,
                                  unsigned short* __restrict__ hi,
                                  unsigned short* __restrict__ lo,
                                  int R, int K8, int idx) {
  int r = idx & 15;
  int t = idx >> 4;
  int kq = t % K8;
  int rb = t / K8;
  int row = rb * 16 + r;
  float v[8] = {0.f, 0.f, 0.f, 0.f, 0.f, 0.f, 0.f, 0.f};
  if (row < R) {
    const float* p = in + (size_t)row * (K8 * 8) + kq * 8;
    float4 a = *(const float4*)p;
    float4 b = *(const float4*)(p + 4);
    v[0] = a.x; v[1] = a.y; v[2] = a.z; v[3] = a.w;
    v[4] = b.x; v[5] = b.y; v[6] = b.z; v[7] = b.w;
  }
  union { unsigned short u[8]; int4 v4; } H, L;
  #pragma unroll
  for (int e = 0; e < 8; ++e) {
    unsigned short hb_ = f2bf_rne(v[e]);
    H.u[e] = hb_;
    L.u[e] = f2bf_rne(v[e] - bf2f(hb_));
  }
  *(int4*)&hi[(size_t)idx * 8] = H.v4;
  if (lo) *(int4*)&lo[(size_t)idx * 8] = L.v4;
}

// Combined A split + W split + CSR degree count in ONE dispatch.
__global__ __launch_bounds__(256)
void split_frag2(const float* __restrict__ in1, unsigned short* __restrict__ hi1,
                 unsigned short* __restrict__ lo1, int R1, int K81, int total1,
                 int nb1,
                 const float* __restrict__ in2, unsigned short* __restrict__ hi2,
                 unsigned short* __restrict__ lo2, int R2, int K82, int total2,
                 int nb2,
                 const int* __restrict__ edst, int* __restrict__ deg, int E) {
  if ((int)blockIdx.x < nb1) {
    int idx = blockIdx.x * 256 + threadIdx.x;
    if (idx < total1) split_body(in1, hi1, lo1, R1, K81, idx);
  } else if ((int)blockIdx.x < nb1 + nb2) {
    int idx = (blockIdx.x - nb1) * 256 + threadIdx.x;
    if (idx < total2) split_body(in2, hi2, lo2, R2, K82, idx);
  } else {
    int e = (blockIdx.x - nb1 - nb2) * 256 + threadIdx.x;
    if (e < E) atomicAdd(&deg[edst[e]], 1);
  }
}

// ---------------------------------------------------------------------------
// LDS-free split-bf16 MFMA GEMM.  A at bf16 only; B hi+lo split.
// R3: K-loop unrolled x2 (BK=64).  R2 showed dur is INVARIANT to per-iter
// work (-33% MFMA, -25% loads -> same 51us): iteration-latency-bound (each
// iter drains its load group before the MFMA block; ~2 waves/SIMD can't
// cover L2 latency).  BK=64 halves the number of latency exposures and
// doubles MLP (24 loads in flight); subtile-0 MFMAs overlap subtile-1 loads
// via the compiler's counted vmcnt.  NT stores REVERTED (R2: 32B granule NT
// -> HBM RMW, WRITE_SIZE 20.7->49MB, and evicted hb from the consumer's L2).
// ---------------------------------------------------------------------------
__global__ __launch_bounds__(128, 2)
void gemm_frag(const unsigned short* __restrict__ Afh,
               const unsigned short* __restrict__ Afl,
               const unsigned short* __restrict__ Bfh,
               const unsigned short* __restrict__ Bfl,
               const float* __restrict__ avec,
               unsigned short* __restrict__ hb,
               float* __restrict__ si, float* __restrict__ sj,
               int M, int K) {
  __shared__ float rsi[64][2];
  __shared__ float rsj[64][2];
  int tid = threadIdx.x;
  int wave = tid >> 6, lane = tid & 63;
  int r = lane & 15, q = lane >> 4;

  int blk = blockIdx.x;
  int rr = blk & 7, gg = blk >> 3;
  int head = gg & 7;
  int mtile = (gg >> 3) * 8 + rr;     // blk%8 == mtile%8 -> XCD affinity
  int m0 = mtile * 64;
  int wn = wave * 64;
  int K8 = K >> 3;

  const bf16x8* pAh = (const bf16x8*)Afh;
  const bf16x8* pBh = (const bf16x8*)Bfh;
  const bf16x8* pBl = (const bf16x8*)Bfl;
  size_t rstep = (size_t)K8 * 16;
  size_t aidx = (size_t)(m0 >> 4) * rstep + (size_t)q * 16 + r;
  size_t bidx = (size_t)(head * 8 + (wn >> 4)) * rstep + (size_t)q * 16 + r;

  f32x4 acc[4][4] = {};

  for (int k0 = 0; k0 < K; k0 += 64, aidx += 128, bidx += 128) {
    bf16x8 ah[8], bh[8], bl[8];
    #pragma unroll
    for (int i = 0; i < 4; ++i) {
      ah[i]     = pAh[aidx + i * rstep];
      bh[i]     = pBh[bidx + i * rstep];
      bl[i]     = pBl[bidx + i * rstep];
      ah[i + 4] = pAh[aidx + i * rstep + 64];
      bh[i + 4] = pBh[bidx + i * rstep + 64];
      bl[i + 4] = pBl[bidx + i * rstep + 64];
    }
    // subtile 0 (k0..k0+31): runs while subtile-1 loads are in flight
    #pragma unroll
    for (int i = 0; i < 4; ++i)
      #pragma unroll
      for (int j = 0; j < 4; ++j) {
        acc[i][j] = __builtin_amdgcn_mfma_f32_16x16x32_bf16(ah[i], bh[j], acc[i][j], 0, 0, 0);
        acc[i][j] = __builtin_amdgcn_mfma_f32_16x16x32_bf16(ah[i], bl[j], acc[i][j], 0, 0, 0);
      }
    // subtile 1 (k0+32..k0+63)
    #pragma unroll
    for (int i = 0; i < 4; ++i)
      #pragma unroll
      for (int j = 0; j < 4; ++j) {
        acc[i][j] = __builtin_amdgcn_mfma_f32_16x16x32_bf16(ah[i + 4], bh[j + 4], acc[i][j], 0, 0, 0);
        acc[i][j] = __builtin_amdgcn_mfma_f32_16x16x32_bf16(ah[i + 4], bl[j + 4], acc[i][j], 0, 0, 0);
      }
  }

  // --- epilogue: C/D layout col = r, row = q*4 + reg (per 16x16 frag) ---
  const float* av = avec + (size_t)head * (2 * HID);
  float aiv[4], ajv[4];
  #pragma unroll
  for (int j = 0; j < 4; ++j) {
    int c = wn + j * 16 + r;
    aiv[j] = av[c];
    ajv[j] = av[HID + c];
  }
  #pragma unroll
  for (int i = 0; i < 4; ++i) {
    #pragma unroll
    for (int reg = 0; reg < 4; ++reg) {
      int lrow = i * 16 + q * 4 + reg;
      int row = m0 + lrow;
      float vsi = 0.f, vsj = 0.f;
      #pragma unroll
      for (int j = 0; j < 4; ++j) {
        float v = acc[i][j][reg];
        vsi = fmaf(v, aiv[j], vsi);
        vsj = fmaf(v, ajv[j], vsj);
        if (row < M)
          hb[((size_t)head * M + row) * HID + wn + j * 16 + r] = f2bf_rne(v);
      }
      #pragma unroll
      for (int o = 8; o >= 1; o >>= 1) {
        vsi += __shfl_xor(vsi, o);
        vsj += __shfl_xor(vsj, o);
      }
      if (r == 0) {
        rsi[lrow][wave] = vsi;
        rsj[lrow][wave] = vsj;
      }
    }
  }
  __syncthreads();
  if (tid < 64) {
    int row = m0 + tid;
    if (row < M) {
      si[(size_t)head * M + row] = rsi[tid][0] + rsi[tid][1];
      sj[(size_t)head * M + row] = rsj[tid][0] + rsj[tid][1];
    }
  }
}

// ---------------------------------------------------------------------------
// CSR build (count fused into split_frag2)
// ---------------------------------------------------------------------------
__global__ __launch_bounds__(1024)
void scan_kernel(const int* __restrict__ deg, int* __restrict__ off, int N) {
  __shared__ int sums[1024];
  const int PER = 10;
  int tid = threadIdx.x;
  int base = tid * PER;
  int loc[PER];
  int run = 0;
  #pragma unroll
  for (int j = 0; j < PER; ++j) {
    int v = (base + j < N) ? deg[base + j] : 0;
    run += v;
    loc[j] = run;
  }
  sums[tid] = run;
  __syncthreads();
  for (int o = 1; o < 1024; o <<= 1) {
    int v = (tid >= o) ? sums[tid - o] : 0;
    __syncthreads();
    sums[tid] += v;
    __syncthreads();
  }
  int ex = sums[tid] - run;
  if (tid == 0) off[0] = 0;
  #pragma unroll
  for (int j = 0; j < PER; ++j)
    if (base + j < N) off[base + j + 1] = ex + loc[j];
}

__global__ void fill_kernel(const int* __restrict__ src, const int* __restrict__ dst,
                            const int* __restrict__ off, int* __restrict__ cursor,
                            int* __restrict__ ssrc, int E) {
  int e = blockIdx.x * blockDim.x + threadIdx.x;
  if (e < E) {
    int d = dst[e];
    int p = atomicAdd(&cursor[d], 1);
    ssrc[off[d] + p] = src[e];
  }
}

// ---------------------------------------------------------------------------
// FUSED softmax + aggregation: one wave = FOUR dst nodes (16 lanes per dst)
// of one head.  head = blk&7 (hb head-plane XCD L2 affinity).
// ---------------------------------------------------------------------------
__global__ __launch_bounds__(512)
void gat_aggregate8(const unsigned short* __restrict__ hb,
                    const float* __restrict__ si, const float* __restrict__ sj,
                    const int* __restrict__ off, const int* __restrict__ ssrc,
                    unsigned short* __restrict__ aggb, int N) {
  __shared__ int2 prs[8][4][32];   // [wave][group][edge-slot] (src, w)
  int head = blockIdx.x & 7;
  int wv = threadIdx.x >> 6;
  int lane = threadIdx.x & 63;
  int grp = lane >> 4;
  int sl = lane & 15;
  int n = (blockIdx.x >> 3) * 32 + wv * 4 + grp;
  const unsigned short* hbase = hb + (size_t)head * N * HID;
  const float* sjh = sj + (size_t)head * N;
  bool nv = n < N;
  int begin = 0, deg = 0;
  float s_i = 0.f;
  if (nv) {
    begin = off[n];
    deg = off[n + 1] - begin;
    s_i = si[(size_t)head * N + n];
  }

  // --- phase 1: per-lane edge scores, 2 slots (covers deg <= 32) ---
  int src0 = 0, src1 = 0;
  float sc0 = -INFINITY, sc1 = -INFINITY;
  if (sl < deg) {
    src0 = ssrc[begin + sl];
    float t = s_i + sjh[src0];
    sc0 = t > 0.f ? t : 0.01f * t;
  }
  if (16 + sl < deg) {
    src1 = ssrc[begin + 16 + sl];
    float t = s_i + sjh[src1];
    sc1 = t > 0.f ? t : 0.01f * t;
  }
  float m = fmaxf(sc0, sc1);
  for (int e2 = 32 + sl; e2 < deg; e2 += 16) {      // rare tail max
    int s = ssrc[begin + e2];
    float t = s_i + sjh[s];
    t = t > 0.f ? t : 0.01f * t;
    m = fmaxf(m, t);
  }
  #pragma unroll
  for (int o = 1; o <= 8; o <<= 1) m = fmaxf(m, __shfl_xor(m, o));

  float w0 = (sl < deg) ? __expf(sc0 - m) : 0.f;
  float w1 = (16 + sl < deg) ? __expf(sc1 - m) : 0.f;
  float den = w0 + w1;
  for (int e2 = 32 + sl; e2 < deg; e2 += 16) {      // rare tail denom
    int s = ssrc[begin + e2];
    float t = s_i + sjh[s];
    t = t > 0.f ? t : 0.01f * t;
    den += __expf(t - m);
  }
  #pragma unroll
  for (int o = 1; o <= 8; o <<= 1) den += __shfl_xor(den, o);

  // stage pairs (w=0 beyond deg; src=0 -> safe dummy gather)
  prs[wv][grp][sl] = make_int2(src0, __float_as_int(w0));
  prs[wv][grp][16 + sl] = make_int2(src1, __float_as_int(w1));
  // wave-synchronous LDS: ensure writes land + block compiler reorder.
  __asm__ volatile("s_waitcnt lgkmcnt(0)" ::: "memory");

  // --- gather: 16 lanes cover the 128-dim row, 4 edges in flight ---
  v2f a01 = {0.f, 0.f}, a23 = {0.f, 0.f}, a45 = {0.f, 0.f}, a67 = {0.f, 0.f};
  int dmin = deg < 32 ? deg : 32;
  for (int e0 = 0; e0 < dmin; e0 += 4) {            // slots e0..e0+3 <= 31 always init'd
    int2 p[4];
    #pragma unroll
    for (int u = 0; u < 4; ++u) p[u] = prs[wv][grp][e0 + u];
    int4 pv[4];
    #pragma unroll
    for (int u = 0; u < 4; ++u)
      pv[u] = *(const int4*)&hbase[(size_t)p[u].x * HID + sl * 8];
    #pragma unroll
    for (int u = 0; u < 4; ++u) {
      float w = __int_as_float(p[u].y);
      v2f w2 = {w, w};
      int4 q = pv[u];
      v2f t0 = {bf2f((unsigned)q.x & 0xffffu), __uint_as_float((unsigned)q.x & 0xffff0000u)};
      v2f t1 = {bf2f((unsigned)q.y & 0xffffu), __uint_as_float((unsigned)q.y & 0xffff0000u)};
      v2f t2 = {bf2f((unsigned)q.z & 0xffffu), __uint_as_float((unsigned)q.z & 0xffff0000u)};
      v2f t3 = {bf2f((unsigned)q.w & 0xffffu), __uint_as_float((unsigned)q.w & 0xffff0000u)};
      a01 += w2 * t0;                 // v_pk_fma_f32
      a23 += w2 * t1;
      a45 += w2 * t2;
      a67 += w2 * t3;
    }
  }
  // rare tail: deg > 32, recompute weight (uniform across the 16-lane group)
  for (int e2 = 32; e2 < deg; ++e2) {
    int s = ssrc[begin + e2];
    float t = s_i + sjh[s];
    t = t > 0.f ? t : 0.01f * t;
    float w = __expf(t - m);
    v2f w2 = {w, w};
    int4 q = *(const int4*)&hbase[(size_t)s * HID + sl * 8];
    v2f t0 = {bf2f((unsigned)q.x & 0xffffu), __uint_as_float((unsigned)q.x & 0xffff0000u)};
    v2f t1 = {bf2f((unsigned)q.y & 0xffffu), __uint_as_float((unsigned)q.y & 0xffff0000u)};
    v2f t2 = {bf2f((unsigned)q.z & 0xffffu), __uint_as_float((unsigned)q.z & 0xffff0000u)};
    v2f t3 = {bf2f((unsigned)q.w & 0xffffu), __uint_as_float((unsigned)q.w & 0xffff0000u)};
    a01 += w2 * t0; a23 += w2 * t1; a45 += w2 * t2; a67 += w2 * t3;
  }

  // --- epilogue: each lane owns 8 dims; all 64 lanes store ---
  if (nv) {
    float inv = den > 0.f ? 1.0f / den : 0.f;
    union { unsigned short u[8]; int4 v4; } P;
    P.u[0] = f2bf_rne(a01.x * inv); P.u[1] = f2bf_rne(a01.y * inv);
    P.u[2] = f2bf_rne(a23.x * inv); P.u[3] = f2bf_rne(a23.y * inv);
    P.u[4] = f2bf_rne(a45.x * inv); P.u[5] = f2bf_rne(a45.y * inv);
    P.u[6] = f2bf_rne(a67.x * inv); P.u[7] = f2bf_rne(a67.y * inv);
    *(int4*)&aggb[((size_t)head * N + n) * HID + sl * 8] = P.v4;
  }
}

// ---------------------------------------------------------------------------
// Head mean + ELU (bf16 aggbuf), writing layer-2 A in frag-major split form
// (hi plane only — gemm consumes A at bf16), FUSED with the W2 split.
// ---------------------------------------------------------------------------
__global__ __launch_bounds__(256)
void headmean_frag_w2(const unsigned short* __restrict__ aggb,
                      unsigned short* __restrict__ hiA,
                      int N, int nbHM,
                      const float* __restrict__ W2, unsigned short* __restrict__ hiB,
                      unsigned short* __restrict__ loB, int totalB) {
  if ((int)blockIdx.x >= nbHM) {
    int idx = (blockIdx.x - nbHM) * 256 + threadIdx.x;
    if (idx < totalB) split_body(W2, hiB, loB, HEADS * HID, 16, idx);
    return;
  }
  int idx = blockIdx.x * 256 + threadIdx.x;   // (rb,kq,r), K8=16
  int total = ((N + 15) / 16) * 256;
  if (idx >= total) return;
  int r = idx & 15;
  int kq = (idx >> 4) & 15;
  int rb = idx >> 8;
  int n = rb * 16 + r;
  float s[8] = {0.f, 0.f, 0.f, 0.f, 0.f, 0.f, 0.f, 0.f};
  if (n < N) {
    #pragma unroll
    for (int hh = 0; hh < HEADS; ++hh) {
      int4 pv = *(const int4*)&aggb[((size_t)hh * N + n) * HID + kq * 8];
      s[0] += bf2f((unsigned)pv.x & 0xffffu);
      s[1] += __uint_as_float((unsigned)pv.x & 0xffff0000u);
      s[2] += bf2f((unsigned)pv.y & 0xffffu);
      s[3] += __uint_as_float((unsigned)pv.y & 0xffff0000u);
      s[4] += bf2f((unsigned)pv.z & 0xffffu);
      s[5] += __uint_as_float((unsigned)pv.z & 0xffff0000u);
      s[6] += bf2f((unsigned)pv.w & 0xffffu);
      s[7] += __uint_as_float((unsigned)pv.w & 0xffff0000u);
    }
  }
  union { unsigned short u[8]; int4 v4; } H;
  #pragma unroll
  for (int e = 0; e < 8; ++e) {
    float v = s[e] * (1.0f / HEADS);
    v = v > 0.f ? v : (__expf(v) - 1.0f);   // ELU
    H.u[e] = f2bf_rne(v);
  }
  *(int4*)&hiA[(size_t)idx * 8] = H.v4;
}

// ---------------------------------------------------------------------------
// Layer-2 tail: head mean + ELU + graph pooling fused (no emb2 materialized).
// ---------------------------------------------------------------------------
__global__ __launch_bounds__(256)
void headmean_pool(const unsigned short* __restrict__ aggb, float* __restrict__ g,
                   int N) {
  __shared__ float sm[16][128];
  int t = threadIdx.x;
  int nl = t >> 4, dg = t & 15;
  int n = blockIdx.x * 16 + nl;
  float v[8] = {0.f, 0.f, 0.f, 0.f, 0.f, 0.f, 0.f, 0.f};
  if (n < N) {
    #pragma unroll
    for (int hh = 0; hh < HEADS; ++hh) {
      int4 pv = *(const int4*)&aggb[((size_t)hh * N + n) * HID + dg * 8];
      v[0] += bf2f((unsigned)pv.x & 0xffffu);
      v[1] += __uint_as_float((unsigned)pv.x & 0xffff0000u);
      v[2] += bf2f((unsigned)pv.y & 0xffffu);
      v[3] += __uint_as_float((unsigned)pv.y & 0xffff0000u);
      v[4] += bf2f((unsigned)pv.z & 0xffffu);
      v[5] += __uint_as_float((unsigned)pv.z & 0xffff0000u);
      v[6] += bf2f((unsigned)pv.w & 0xffffu);
      v[7] += __uint_as_float((unsigned)pv.w & 0xffff0000u);
    }
    #pragma unroll
    for (int e = 0; e < 8; ++e) {
      float x = v[e] * (1.0f / HEADS);
      v[e] = x > 0.f ? x : (__expf(x) - 1.0f);   // ELU
    }
  }
  #pragma unroll
  for (int e = 0; e < 8; ++e) sm[nl][dg * 8 + e] = v[e];
  __syncthreads();
  if (t < 128) {
    float s = 0.f;
    #pragma unroll
    for (int nn = 0; nn < 16; ++nn) s += sm[nn][t];
    atomicAdd(&g[t], s);
  }
}

// ---------------------------------------------------------------------------
// LayerNorm + MLP head
// ---------------------------------------------------------------------------
__global__ __launch_bounds__(128)
void mlp_kernel(const float* __restrict__ g, const float* __restrict__ ln_g,
                const float* __restrict__ ln_b, const float* __restrict__ Wl1,
                const float* __restrict__ bl1, const float* __restrict__ Wl2,
                const float* __restrict__ bl2, const float* __restrict__ Wl3,
                const float* __restrict__ bl3, float* __restrict__ out, float invN) {
  __shared__ float red[128];
  __shared__ float gn[128];
  __shared__ float x1[64];
  __shared__ float x2[16];
  int t = threadIdx.x;
  float gg = g[t] * invN;
  red[t] = gg;
  __syncthreads();
  for (int o = 64; o > 0; o >>= 1) {
    if (t < o) red[t] += red[t + o];
    __syncthreads();
  }
  float mu = red[0] * (1.0f / HID);
  __syncthreads();
  float dv = gg - mu;
  red[t] = dv * dv;
  __syncthreads();
  for (int o = 64; o > 0; o >>= 1) {
    if (t < o) red[t] += red[t + o];
    __syncthreads();
  }
  float var = red[0] * (1.0f / HID);
  gn[t] = dv / sqrtf(var + 1e-5f) * ln_g[t] + ln_b[t];
  __syncthreads();
  if (t < 64) {
    float s = bl1[t];
    for (int k = 0; k < 128; ++k) s += Wl1[t * 128 + k] * gn[k];
    x1[t] = s > 0.f ? s : 0.01f * s;
  }
  __syncthreads();
  if (t < 16) {
    float s = bl2[t];
    for (int k = 0; k < 64; ++k) s += Wl2[t * 64 + k] * x1[k];
    x2[t] = s > 0.f ? s : 0.01f * s;
  }
  __syncthreads();
  if (t < 16) {
    float s = bl3[t];
    for (int k = 0; k < 16; ++k) s += Wl3[t * 16 + k] * x2[k];
    out[t] = s > 0.f ? s : 0.f;
  }
}

// ---------------------------------------------------------------------------
extern "C" void kernel_launch(void* const* d_in, const int* in_sizes, int n_in,
                              void* d_out, int out_size, void* d_ws, size_t ws_size,
                              hipStream_t stream) {
  const float* x    = (const float*)d_in[0];
  const int*   esrc = (const int*)d_in[1];
  const int*   edst = (const int*)d_in[2];
  const float* W1   = (const float*)d_in[3];
  const float* a1   = (const float*)d_in[4];
  const float* W2   = (const float*)d_in[5];
  const float* a2   = (const float*)d_in[6];
  const float* ln_g = (const float*)d_in[7];
  const float* ln_b = (const float*)d_in[8];
  const float* Wl1  = (const float*)d_in[9];
  const float* bl1  = (const float*)d_in[10];
  const float* Wl2  = (const float*)d_in[11];
  const float* bl2  = (const float*)d_in[12];
  const float* Wl3  = (const float*)d_in[13];
  const float* bl3  = (const float*)d_in[14];
  float* out = (float*)d_out;

  const int RBPAD = 640;  // row-blocks padded (10240 rows) for in-bounds frags

  // workspace carve-up (g, deg, cur contiguous -> one memset)
  unsigned short* aggb = (unsigned short*)d_ws;                 // 20.5 MB
  float* si   = (float*)(aggb + (size_t)N_NODES * HEADS * HID); // 80,000
  float* sj   = si + N_NODES * HEADS;                           // 80,000
  float* g    = sj + N_NODES * HEADS;                           // 128
  int*   deg  = (int*)(g + 128);                                // 10,000
  int*   cur  = deg + N_NODES;                                  // 10,000
  int*   off  = cur + N_NODES;                                  // 10,001 -> pad 10,004
  int*   ssrc = off + 10004;                                    // 160,000
  unsigned short* Afh = (unsigned short*)(ssrc + N_EDGES);      // 640*64*128 us
  unsigned short* Afl = Afh + (size_t)RBPAD * 64 * 128;         // (unused by gemm now)
  unsigned short* Bfh = Afl + (size_t)RBPAD * 64 * 128;
  unsigned short* Bfl = Bfh + (size_t)64 * 64 * 128;
  unsigned short* hb  = Bfl + (size_t)64 * 64 * 128;            // 20.5 MB

  // zero g + deg + cur in ONE memset (contiguous)
  hipMemsetAsync(g, 0, 128 * sizeof(float) + 2 * N_NODES * sizeof(int), stream);

  int gemmGrid = 160 * HEADS;                     // 1280 blocks of 128 threads
  int aggGrid = ((N_NODES + 31) / 32) * 8;        // 2504 blocks: 32 dst x 1 head each

  // ---- Layer 1: fused A-split + W1-split + CSR count in one dispatch ----
  {
    int totalA = RBPAD * 64 * 16;             // K8=64
    int nbA = (totalA + 255) / 256;           // 2560
    int totalB = 64 * 64 * 16;                // 1024 rows, K8=64
    int nbB = (totalB + 255) / 256;           // 256
    int nbE = (N_EDGES + 255) / 256;          // 625
    split_frag2<<<nbA + nbB + nbE, 256, 0, stream>>>(
        x, Afh, (unsigned short*)nullptr, N_NODES, 64, totalA, nbA,
        W1, Bfh, Bfl, HEADS * HID, 64, totalB, nbB,
        edst, deg, N_EDGES);
  }
  scan_kernel<<<1, 1024, 0, stream>>>(deg, off, N_NODES);
  fill_kernel<<<(N_EDGES + 255) / 256, 256, 0, stream>>>(esrc, edst, off, cur, ssrc, N_EDGES);

  gemm_frag<<<gemmGrid, 128, 0, stream>>>(Afh, Afl, Bfh, Bfl, a1, hb,
                                          si, sj, N_NODES, N_FEAT);
  gat_aggregate8<<<aggGrid, 512, 0, stream>>>(hb, si, sj, off, ssrc, aggb, N_NODES);
  {
    int nbHM = ((N_NODES + 15) / 16 * 256 + 255) / 256;   // 625
    int totalB = 64 * 16 * 16;                            // W2: 1024 rows, K8=16
    int nbB = (totalB + 255) / 256;                       // 64
    headmean_frag_w2<<<nbHM + nbB, 256, 0, stream>>>(aggb, Afh, N_NODES, nbHM,
                                                     W2, Bfh, Bfl, totalB);
  }

  // ---- Layer 2 ----
  gemm_frag<<<gemmGrid, 128, 0, stream>>>(Afh, Afl, Bfh, Bfl, a2, hb,
                                          si, sj, N_NODES, HID);
  gat_aggregate8<<<aggGrid, 512, 0, stream>>>(hb, si, sj, off, ssrc, aggb, N_NODES);

  // ---- fused head-mean + pooling + MLP head ----
  headmean_pool<<<(N_NODES + 15) / 16, 256, 0, stream>>>(aggb, g, N_NODES);
  mlp_kernel<<<1, 128, 0, stream>>>(g, ln_g, ln_b, Wl1, bl1, Wl2, bl2, Wl3, bl3,
                                    out, 1.0f / N_NODES);
}